// Round 11
// baseline (224.810 us; speedup 1.0000x reference)
//
#include <hip/hip_runtime.h>
#include <stdint.h>

#define BATCH 2
#define SEQ 2048
#define DMODEL 1024
#define NHEAD 16
#define HDIM 64
#define CVTW_BLOCKS 3072

typedef __attribute__((ext_vector_type(8))) short bf16x8;
typedef __attribute__((ext_vector_type(4))) float f32x4;

__device__ __forceinline__ unsigned short f2bf(float f) {
  unsigned int u = __float_as_uint(f);
  u += 0x7fffu + ((u >> 16) & 1u);
  return (unsigned short)(u >> 16);
}
// pack 2 f32 -> 2 bf16 (round-to-nearest-ties-away): 2 adds + 1 v_perm
__device__ __forceinline__ unsigned int pk2bf(float a, float b) {
  return __builtin_amdgcn_perm(__float_as_uint(b) + 0x8000u,
                               __float_as_uint(a) + 0x8000u, 0x07060302u);
}
__device__ __forceinline__ void async_copy16(const void* g, void* l) {
  __builtin_amdgcn_global_load_lds(
      (const __attribute__((address_space(1))) void*)g,
      (__attribute__((address_space(3))) void*)l, 16, 0, 0);
}

// ---- cvt_w: fp32 -> bf16 for Wq,Wk,Wv only; block CVTW_BLOCKS computes lens.
// (q,k,v conversion is fused into qkv_proj -> saves ~90MB of HBM round-trip.)
__global__ __launch_bounds__(256) void cvt_w(
    const float* __restrict__ Wq, const float* __restrict__ Wk,
    const float* __restrict__ Wv, unsigned short* __restrict__ dst,
    const unsigned char* __restrict__ kp, const unsigned char* __restrict__ qp,
    int* __restrict__ lens) {
  if (blockIdx.x == CVTW_BLOCKS) {  // klen->lens[0..1], qlen->lens[2..3]
    const int t = threadIdx.x, wave = t >> 6, lane = t & 63;
    const unsigned char* base = (wave < 2) ? kp : qp;
    const int b = wave & 1;
    const bool bytefmt = (base[1] != 0);  // element 1 always valid (len>=S/2)
    int cnt = 0;
    if (bytefmt) {
      const uint4* p = (const uint4*)(base + (size_t)b * SEQ);
#pragma unroll
      for (int g = 0; g < 2; g++) {
        const uint4 x = p[g * 64 + lane];
        const unsigned int w[4] = {x.x, x.y, x.z, x.w};
#pragma unroll
        for (int i = 0; i < 4; i++) {
          const unsigned int ww = w[i];
          cnt += ((ww & 0xffu) != 0) + ((ww & 0xff00u) != 0) +
                 ((ww & 0xff0000u) != 0) + ((ww & 0xff000000u) != 0);
        }
      }
    } else {
      const uint4* p = (const uint4*)(base + (size_t)b * SEQ * 4);
#pragma unroll
      for (int g = 0; g < 8; g++) {
        const uint4 x = p[g * 64 + lane];
        cnt += (x.x != 0) + (x.y != 0) + (x.z != 0) + (x.w != 0);
      }
    }
#pragma unroll
    for (int off = 32; off >= 1; off >>= 1) cnt += __shfl_xor(cnt, off, 64);
    if (lane == 0) lens[wave] = cnt;
    return;
  }
  const int g = blockIdx.x * 256 + threadIdx.x;  // 0 .. 3*2^18-1 float4 slots
  const int ti = g >> 18;
  const size_t off = (size_t)(g & ((1 << 18) - 1));
  const float* src = (ti == 0) ? Wq : (ti == 1) ? Wk : Wv;
  const float4 x = ((const float4*)src)[off];
  ushort4 o;
  o.x = f2bf(x.x); o.y = f2bf(x.y); o.z = f2bf(x.z); o.w = f2bf(x.w);
  *(ushort4*)(dst + ((size_t)ti << 20) + off * 4) = o;
}

// ---- fused QKV projection v3: x read as FP32 + in-register cvt (cvt fused).
// A (x): reg-staged — load 2xfloat4, 4x pk2bf, 1x ds_write_b128; loads issued
// BEFORE the barrier (T14 issue-early) so HBM/L2 latency hides under previous
// compute. LDS layout byte-identical to async path -> compute unchanged.
// B (W): async global_load_lds from bf16 (cvt_w). Q pre-scaled by
// (1/sqrt(64))*log2(e). Q/K swapped mfma, V normal -> V^T[b,h,d,s].
__global__ __launch_bounds__(256) void qkv_proj(
    const float* __restrict__ xq, const float* __restrict__ xk,
    const float* __restrict__ xv,
    const unsigned short* __restrict__ Wq, const float* __restrict__ bq,
    const unsigned short* __restrict__ Wk, const float* __restrict__ bk,
    const unsigned short* __restrict__ Wv, const float* __restrict__ bv,
    unsigned short* __restrict__ Qo, unsigned short* __restrict__ Ko,
    unsigned short* __restrict__ Vo, const int* __restrict__ lens) {
  const int z = blockIdx.z;
  const int m0 = blockIdx.y * 128, n0 = blockIdx.x * 128;
  const int b = m0 >> 11;
  const int len = (z == 0) ? lens[2 + b] : lens[b];
  if ((m0 & (SEQ - 1)) >= len) return;  // rows never read downstream (poison benign)

  const float* x = (z == 0) ? xq : (z == 1) ? xk : xv;
  const unsigned short* W = (z == 0) ? Wq : (z == 1) ? Wk : Wv;
  const float* bias = (z == 0) ? bq : (z == 1) ? bk : bv;
  unsigned short* dst = (z == 0) ? Qo : (z == 1) ? Ko : Vo;
  const float osc = (z == 0) ? 0.18033688011112042f : 1.0f;

  __shared__ unsigned short As[128 * 64];  // row=64 shorts, 8x16B groups, swizzle row&7
  __shared__ unsigned short Bs[128 * 64];

  const int t = threadIdx.x;
  const int wave = t >> 6, lane = t & 63, quad = lane >> 4, l16 = lane & 15;
  const int wm = wave >> 1, wn = wave & 1;

  const f32x4 fz = {0.f, 0.f, 0.f, 0.f};
  f32x4 acc[4][4];
#pragma unroll
  for (int i = 0; i < 4; i++)
#pragma unroll
    for (int j = 0; j < 4; j++) acc[i][j] = fz;

  for (int k0 = 0; k0 < DMODEL; k0 += 64) {
    // A: load fp32 + convert in regs (no LDS access -> overlaps prev compute)
    uint4 av[4];
#pragma unroll
    for (int c = 0; c < 4; c++) {
      const int slot = c * 256 + t;
      const int row = slot >> 3, pg = slot & 7;
      const int lg = (pg ^ (row & 7)) * 8;
      const float4* pa = (const float4*)(x + (size_t)(m0 + row) * DMODEL + k0 + lg);
      const float4 a0 = pa[0], a1 = pa[1];
      av[c].x = pk2bf(a0.x, a0.y);
      av[c].y = pk2bf(a0.z, a0.w);
      av[c].z = pk2bf(a1.x, a1.y);
      av[c].w = pk2bf(a1.z, a1.w);
    }
    __syncthreads();  // previous compute finished reading As/Bs
#pragma unroll
    for (int c = 0; c < 4; c++) {
      const int slot = c * 256 + t;
      *(uint4*)((char*)As + slot * 16) = av[c];
      const int row = slot >> 3, pg = slot & 7;
      const int lg = (pg ^ (row & 7)) * 8;
      async_copy16(W + (size_t)(n0 + row) * DMODEL + k0 + lg,
                   (char*)Bs + (c * 256 + (t & 192)) * 16);
    }
    __syncthreads();  // drains ds_writes (lgkm) + async B (vmcnt)
#pragma unroll
    for (int kk = 0; kk < 2; kk++) {
      bf16x8 af[4], bfr[4];
#pragma unroll
      for (int i = 0; i < 4; i++) {
        const int ra = wm * 64 + i * 16 + l16;
        const int rb = wn * 64 + i * 16 + l16;
        af[i] = *(const bf16x8*)(As + ra * 64 + ((kk * 4 + quad) ^ (ra & 7)) * 8);
        bfr[i] = *(const bf16x8*)(Bs + rb * 64 + ((kk * 4 + quad) ^ (rb & 7)) * 8);
      }
      if (z == 2) {
#pragma unroll
        for (int i = 0; i < 4; i++)
#pragma unroll
          for (int j = 0; j < 4; j++)
            acc[i][j] = __builtin_amdgcn_mfma_f32_16x16x32_bf16(af[i], bfr[j], acc[i][j], 0, 0, 0);
      } else {
#pragma unroll
        for (int i = 0; i < 4; i++)
#pragma unroll
          for (int j = 0; j < 4; j++)
            acc[i][j] = __builtin_amdgcn_mfma_f32_16x16x32_bf16(bfr[j], af[i], acc[i][j], 0, 0, 0);
      }
    }
  }

  if (z == 2) {
    // acc rows (quad*4+r) = s, cols (l16) = n -> V^T[b,h,hd,s]: 4 consecutive s
#pragma unroll
    for (int j = 0; j < 4; j++) {
      const int n = n0 + wn * 64 + j * 16 + l16;
      const float bb_ = bias[n];
      const int h = n >> 6, hd = n & 63;
#pragma unroll
      for (int i = 0; i < 4; i++) {
        const int s0 = (m0 & (SEQ - 1)) + wm * 64 + i * 16 + quad * 4;
        uint2 w;
        w.x = pk2bf(acc[i][j][0] + bb_, acc[i][j][1] + bb_);
        w.y = pk2bf(acc[i][j][2] + bb_, acc[i][j][3] + bb_);
        *(uint2*)(dst + (((size_t)(b * NHEAD + h) * HDIM + hd) << 11) + s0) = w;
      }
    }
  } else {
    // acc rows (quad*4+r) = n, cols (l16) = s -> [b,h,s,hd]: 4 consecutive hd
#pragma unroll
    for (int j = 0; j < 4; j++) {
      const int nb = n0 + wn * 64 + j * 16 + quad * 4;
      const float4 b4 = *(const float4*)(bias + nb);
      const int h = nb >> 6, hd0 = nb & 63;
#pragma unroll
      for (int i = 0; i < 4; i++) {
        const int s = (m0 & (SEQ - 1)) + wm * 64 + i * 16 + l16;
        uint2 w;
        w.x = pk2bf((acc[i][j][0] + b4.x) * osc, (acc[i][j][1] + b4.y) * osc);
        w.y = pk2bf((acc[i][j][2] + b4.z) * osc, (acc[i][j][3] + b4.w) * osc);
        *(uint2*)(dst + (((size_t)(b * NHEAD + h) * SEQ + s) << 6) + hd0) = w;
      }
    }
  }
}

// ===== attention v11 (R5, best measured 50.2us): ADJACENT tile pairs ========
// pair (2p, 2p+1) on wave groups 0-3/4-7: ktots differ by <=1, every staged
// tile serves both groups; Sigma iters/bh = 272. Cost balance p = b ? x : 15-x.
// KVB=64 dbuf single-barrier pipeline + defer-max + setprio. 48KB -> 2 blk/CU.

#define KVB 64

template <bool MASKED>
__device__ __forceinline__ void softmax_update(
    const f32x4 s[4], int key0, int qrow, int klen, int quad, int l16,
    float& mst, float& lsum, f32x4 o[4], unsigned short* Pdst) {
  float pm[4][4];
  float rm = -__builtin_inff();
  if (MASKED) {
    const int kmax = ((qrow < klen - 1) ? qrow : klen - 1) - key0 - quad * 4;
#pragma unroll
    for (int nf = 0; nf < 4; nf++)
#pragma unroll
      for (int r = 0; r < 4; r++) {
        pm[nf][r] = (nf * 16 + r <= kmax) ? s[nf][r] : -__builtin_inff();
        rm = fmaxf(rm, pm[nf][r]);
      }
  } else {
#pragma unroll
    for (int nf = 0; nf < 4; nf++)
#pragma unroll
      for (int r = 0; r < 4; r++) {
        pm[nf][r] = s[nf][r];
        rm = fmaxf(rm, pm[nf][r]);
      }
  }
  // combine the 4 quads of each q-row (row = l16): lanes l16, +16, +32, +48
  rm = fmaxf(rm, __shfl_xor(rm, 16, 64));
  rm = fmaxf(rm, __shfl_xor(rm, 32, 64));
  // defer-max (T13): rescale only when any row grows by >8 in exp2-domain;
  // otherwise P <= 2^8 = 256, safe for f32 lsum/o accumulation.
  if (__ballot(rm > mst + 8.0f) != 0ull) {
    const float mnew = fmaxf(mst, rm);
    const float alpha = exp2f(fmaxf(mst, -1e30f) - fmaxf(mnew, -1e30f));
    mst = mnew;
    lsum *= alpha;
    float ab[4];
#pragma unroll
    for (int r = 0; r < 4; r++) ab[r] = __shfl(alpha, quad * 4 + r, 64);
#pragma unroll
    for (int db = 0; db < 4; db++)
#pragma unroll
      for (int r = 0; r < 4; r++) o[db][r] *= ab[r];
  }
  const float mref = fmaxf(mst, -1e30f);
  float rs = 0.f;
#pragma unroll
  for (int nf = 0; nf < 4; nf++)
#pragma unroll
    for (int r = 0; r < 4; r++) {
      const float p = exp2f(pm[nf][r] - mref);
      pm[nf][r] = p;
      rs += p;
    }
  rs += __shfl_xor(rs, 16, 64);
  rs += __shfl_xor(rs, 32, 64);
  lsum += rs;
  // P[q=l16][key=16nf+4quad+r] -> 16B group g=2nf+(quad>>1), half (quad&1)
#pragma unroll
  for (int nf = 0; nf < 4; nf++) {
    uint2 w;
    w.x = pk2bf(pm[nf][0], pm[nf][1]);
    w.y = pk2bf(pm[nf][2], pm[nf][3]);
    const int g = (nf * 2 + (quad >> 1)) ^ (l16 & 7);
    *(uint2*)(Pdst + l16 * KVB + g * 8 + (quad & 1) * 4) = w;
  }
}

template <bool MASKED>
__device__ __forceinline__ void tile_pass(
    const unsigned short* __restrict__ ks, const unsigned short* __restrict__ vt,
    unsigned short* __restrict__ Pw, bf16x8 qf0, bf16x8 qf1,
    int key0, int qrow, int klen, int quad, int l16,
    float& mst, float& lsum, f32x4 o[4]) {
  const f32x4 fz = {0.f, 0.f, 0.f, 0.f};
  f32x4 s[4];
  __builtin_amdgcn_s_setprio(1);
#pragma unroll
  for (int nf = 0; nf < 4; nf++) {
    const int row = nf * 16 + l16;
    const int sw = row & 7;
    const bf16x8 kf0 = *(const bf16x8*)(ks + row * 64 + (quad ^ sw) * 8);
    const bf16x8 kf1 = *(const bf16x8*)(ks + row * 64 + ((quad + 4) ^ sw) * 8);
    f32x4 a = fz;
    a = __builtin_amdgcn_mfma_f32_16x16x32_bf16(kf0, qf0, a, 0, 0, 0);
    a = __builtin_amdgcn_mfma_f32_16x16x32_bf16(kf1, qf1, a, 0, 0, 0);
    s[nf] = a;
  }
  __builtin_amdgcn_s_setprio(0);
  softmax_update<MASKED>(s, key0, qrow, klen, quad, l16, mst, lsum, o, Pw);
  bf16x8 pf[2];
#pragma unroll
  for (int ksn = 0; ksn < 2; ksn++)
    pf[ksn] = *(const bf16x8*)(Pw + l16 * KVB + ((ksn * 4 + quad) ^ (l16 & 7)) * 8);
  __builtin_amdgcn_s_setprio(1);
#pragma unroll
  for (int db = 0; db < 4; db++) {
    const int d = db * 16 + l16;
    const int sw = d & 7;
#pragma unroll
    for (int ksn = 0; ksn < 2; ksn++) {
      const bf16x8 v = *(const bf16x8*)(vt + d * KVB + ((ksn * 4 + quad) ^ sw) * 8);
      o[db] = __builtin_amdgcn_mfma_f32_16x16x32_bf16(pf[ksn], v, o[db], 0, 0, 0);
    }
  }
  __builtin_amdgcn_s_setprio(0);
}

__global__ __launch_bounds__(512, 2) void attn_kernel(
    const unsigned short* __restrict__ Qb, const unsigned short* __restrict__ Kb,
    const unsigned short* __restrict__ VTb, const float* __restrict__ qin,
    const int* __restrict__ lens, float* __restrict__ out) {
  const int pi = blockIdx.x, h = blockIdx.y, b = blockIdx.z;
  const int bh = b * NHEAD + h;
  const int t = threadIdx.x, wave = t >> 6, lane = t & 63, quad = lane >> 4, l16 = lane & 15;
  const int grp = wave >> 2, w4 = wave & 3;  // grp 0: tile 2p, grp 1: tile 2p+1
  const int x = (pi + h) & 15;
  const int p = b ? x : 15 - x;  // b=0 half dispatches first: big blocks first
  const int myTile = 2 * p + grp;
  const int klen = lens[b], qlen = lens[2 + b];

  __shared__ unsigned short Ks[2][KVB * 64];  // [key][d], swizzle row&7, 8KB each
  __shared__ unsigned short VT[2][KVB * 64];  // [d][key], swizzle d&7, 8KB each
  __shared__ unsigned short Ps[8][16 * KVB];  // per-wave P, 2KB each
  // total 48KB

  const unsigned short* Qp = Qb + (size_t)bh * SEQ * HDIM;
  const unsigned short* Kp = Kb + (size_t)bh * SEQ * HDIM;
  const unsigned short* Vt = VTb + (size_t)bh * HDIM * SEQ;

  const int qrow = myTile * 64 + w4 * 16 + l16;
  const bf16x8 qf0 = *(const bf16x8*)(Qp + (size_t)qrow * HDIM + quad * 8);
  const bf16x8 qf1 = *(const bf16x8*)(Qp + (size_t)qrow * HDIM + 32 + quad * 8);

  const f32x4 fz = {0.f, 0.f, 0.f, 0.f};
  f32x4 o[4];
#pragma unroll
  for (int i = 0; i < 4; i++) o[i] = fz;
  float mst = -__builtin_inff(), lsum = 0.f;

  // per-group iteration counts in 64-key units (adjacent tiles: differ by <=1)
  const int tA = 2 * p, tB = 2 * p + 1;
  const int kendA = ((tA * 64 + 64) < klen) ? (tA * 64 + 64) : klen;
  const int kendB = ((tB * 64 + 64) < klen) ? (tB * 64 + 64) : klen;
  const int ktA = (tA * 64 < qlen) ? ((kendA + 63) >> 6) : 0;
  const int ktB = (tB * 64 < qlen) ? ((kendB + 63) >> 6) : 0;
  const int ktot = (ktA > ktB) ? ktA : ktB;
  const int myt = grp ? ktB : ktA;

  // stage K/V 64-key tile kt into buffer buf: 512 threads x (1 K + 1 V)
  auto STAGE = [&](int buf, int kt) {
    const int key0 = kt << 6;
    const int row = t >> 3;
    const int sg = ((t & 7) ^ (row & 7)) * 8;  // pre-swizzled source (rule 21)
    async_copy16(Kp + (size_t)(key0 + row) * HDIM + sg,
                 (char*)Ks[buf] + (t & 448) * 16);
    async_copy16(Vt + (size_t)row * SEQ + key0 + sg,
                 (char*)VT[buf] + (t & 448) * 16);
  };

  STAGE(0, 0);
  __syncthreads();  // drains vmcnt(0): buf0 ready
  int cur = 0;
  for (int kt = 0; kt < ktot; kt++) {
    if (kt + 1 < ktot) STAGE(cur ^ 1, kt + 1);  // overlaps with compute below
    if (kt < myt) {
      const int key0 = kt << 6;
      if ((key0 + 63 <= myTile * 64 + w4 * 16) && (key0 + 63 < klen))
        tile_pass<false>(Ks[cur], VT[cur], Ps[wave], qf0, qf1, key0, qrow,
                         klen, quad, l16, mst, lsum, o);
      else
        tile_pass<true>(Ks[cur], VT[cur], Ps[wave], qf0, qf1, key0, qrow,
                        klen, quad, l16, mst, lsum, o);
    }
    __syncthreads();  // drains next-tile staging + all LDS reads of cur
    cur ^= 1;
  }

  const float inv = (lsum > 0.f) ? 1.f / lsum : 0.f;
  float ib[4];
#pragma unroll
  for (int r = 0; r < 4; r++) ib[r] = __shfl(inv, quad * 4 + r, 64);
#pragma unroll
  for (int db = 0; db < 4; db++) {
    const int col = h * HDIM + db * 16 + l16;
#pragma unroll
    for (int r = 0; r < 4; r++) {
      const int i = myTile * 64 + w4 * 16 + quad * 4 + r;
      const size_t oo = (size_t)(b * SEQ + i) * DMODEL + col;
      out[oo] = ((i < qlen) ? o[db][r] * ib[r] : 0.f) + qin[oo];
    }
  }
}

extern "C" void kernel_launch(void* const* d_in, const int* in_sizes, int n_in,
                              void* d_out, int out_size, void* d_ws, size_t ws_size,
                              hipStream_t stream) {
  (void)in_sizes; (void)n_in; (void)out_size; (void)ws_size;
  const float* q = (const float*)d_in[0];
  const float* k = (const float*)d_in[1];
  const float* v = (const float*)d_in[2];
  const float* Wq = (const float*)d_in[3];
  const float* bq = (const float*)d_in[4];
  const float* Wk = (const float*)d_in[5];
  const float* bk = (const float*)d_in[6];
  const float* Wv = (const float*)d_in[7];
  const float* bv = (const float*)d_in[8];
  const unsigned char* kpm = (const unsigned char*)d_in[9];
  const unsigned char* qpm = (const unsigned char*)d_in[10];
  float* out = (float*)d_out;

  const size_t tsz = (size_t)BATCH * SEQ * DMODEL;  // 4 Mi shorts
  const size_t wsz = (size_t)DMODEL * DMODEL;       // 1 Mi shorts

  char* ws = (char*)d_ws;
  int* lens = (int*)ws;
  unsigned short* Wqb = (unsigned short*)(ws + 256);
  unsigned short* Wkb = Wqb + wsz;
  unsigned short* Wvb = Wkb + wsz;
  unsigned short* Qw = Wvb + wsz;
  unsigned short* Kw = Qw + tsz;
  unsigned short* Vtw = Kw + tsz;  // V^T [b,h,d,s]

  cvt_w<<<dim3(CVTW_BLOCKS + 1), dim3(256), 0, stream>>>(Wq, Wk, Wv, Wqb, kpm, qpm, lens);
  qkv_proj<<<dim3(8, 32, 3), dim3(256), 0, stream>>>(q, k, v, Wqb, bq, Wkb, bk, Wvb, bv, Qw, Kw, Vtw, lens);
  attn_kernel<<<dim3(16, NHEAD, BATCH), dim3(512), 0, stream>>>(Qw, Kw, Vtw, q, lens, out);
}

// Round 12
// 202.447 us; speedup vs baseline: 1.1105x; 1.1105x over previous
//
#include <hip/hip_runtime.h>
#include <stdint.h>

#define BATCH 2
#define SEQ 2048
#define DMODEL 1024
#define NHEAD 16
#define HDIM 64
#define CVT_BLOCKS 7680

typedef __attribute__((ext_vector_type(8))) short bf16x8;
typedef __attribute__((ext_vector_type(8))) short short8;
typedef __attribute__((ext_vector_type(4))) float f32x4;

__device__ __forceinline__ unsigned short f2bf(float f) {
  unsigned int u = __float_as_uint(f);
  u += 0x7fffu + ((u >> 16) & 1u);
  return (unsigned short)(u >> 16);
}
// pack 2 f32 -> 2 bf16 (round-to-nearest-ties-away): 2 adds + 1 v_perm
__device__ __forceinline__ unsigned int pk2bf(float a, float b) {
  return __builtin_amdgcn_perm(__float_as_uint(b) + 0x8000u,
                               __float_as_uint(a) + 0x8000u, 0x07060302u);
}
__device__ __forceinline__ void async_copy16(const void* g, void* l) {
  __builtin_amdgcn_global_load_lds(
      (const __attribute__((address_space(1))) void*)g,
      (__attribute__((address_space(3))) void*)l, 16, 0, 0);
}

// ---- fp32 -> bf16 for q,k,v,Wq,Wk,Wv (32B/lane); block CVT_BLOCKS: lens ----
__global__ __launch_bounds__(256) void cvt_all(
    const float* __restrict__ q, const float* __restrict__ k,
    const float* __restrict__ v, const float* __restrict__ Wq,
    const float* __restrict__ Wk, const float* __restrict__ Wv,
    unsigned short* __restrict__ dst,
    const unsigned char* __restrict__ kp, const unsigned char* __restrict__ qp,
    int* __restrict__ lens) {
  if (blockIdx.x == CVT_BLOCKS) {  // klen->lens[0..1], qlen->lens[2..3]
    const int t = threadIdx.x, wave = t >> 6, lane = t & 63;
    const unsigned char* base = (wave < 2) ? kp : qp;
    const int b = wave & 1;
    const bool bytefmt = (base[1] != 0);  // element 1 always valid (len>=S/2)
    int cnt = 0;
    if (bytefmt) {
      const uint4* p = (const uint4*)(base + (size_t)b * SEQ);
#pragma unroll
      for (int g = 0; g < 2; g++) {
        const uint4 x = p[g * 64 + lane];
        const unsigned int w[4] = {x.x, x.y, x.z, x.w};
#pragma unroll
        for (int i = 0; i < 4; i++) {
          const unsigned int ww = w[i];
          cnt += ((ww & 0xffu) != 0) + ((ww & 0xff00u) != 0) +
                 ((ww & 0xff0000u) != 0) + ((ww & 0xff000000u) != 0);
        }
      }
    } else {
      const uint4* p = (const uint4*)(base + (size_t)b * SEQ * 4);
#pragma unroll
      for (int g = 0; g < 8; g++) {
        const uint4 x = p[g * 64 + lane];
        cnt += (x.x != 0) + (x.y != 0) + (x.z != 0) + (x.w != 0);
      }
    }
#pragma unroll
    for (int off = 32; off >= 1; off >>= 1) cnt += __shfl_xor(cnt, off, 64);
    if (lane == 0) lens[wave] = cnt;
    return;
  }
  const int g = blockIdx.x * 256 + threadIdx.x;
  const float* src;
  size_t off, dbase;  // off in float4 units (2 consecutive per thread)
  if (g < 3 * (1 << 19)) {
    const int ti = g >> 19;
    src = (ti == 0) ? q : (ti == 1) ? k : v;
    off = (size_t)(g & ((1 << 19) - 1)) * 2;
    dbase = (size_t)ti << 22;
  } else {
    const int gw = g - 3 * (1 << 19);
    const int ti = gw >> 17;
    src = (ti == 0) ? Wq : (ti == 1) ? Wk : Wv;
    off = (size_t)(gw & ((1 << 17) - 1)) * 2;
    dbase = (3ull << 22) + ((size_t)ti << 20);
  }
  const float4 x0 = ((const float4*)src)[off];
  const float4 x1 = ((const float4*)src)[off + 1];
  short8 o;
  o[0] = (short)f2bf(x0.x); o[1] = (short)f2bf(x0.y);
  o[2] = (short)f2bf(x0.z); o[3] = (short)f2bf(x0.w);
  o[4] = (short)f2bf(x1.x); o[5] = (short)f2bf(x1.y);
  o[6] = (short)f2bf(x1.z); o[7] = (short)f2bf(x1.w);
  *(short8*)(dst + dbase + off * 4) = o;
}

// ---- fused QKV projection v2 (R5-proven): BK=64, swizzled LDS, async A+B.
// Q pre-scaled by (1/sqrt(64))*log2(e). Q/K: swapped mfma -> acc rows = out-dim
// (4 in-lane elems = consecutive hd). V: normal mfma -> acc rows = seq
// (4 in-lane elems = consecutive s) -> writes V^T[b,h,d,s].
__global__ __launch_bounds__(256) void qkv_proj(
    const unsigned short* __restrict__ xq, const unsigned short* __restrict__ xk,
    const unsigned short* __restrict__ xv,
    const unsigned short* __restrict__ Wq, const float* __restrict__ bq,
    const unsigned short* __restrict__ Wk, const float* __restrict__ bk,
    const unsigned short* __restrict__ Wv, const float* __restrict__ bv,
    unsigned short* __restrict__ Qo, unsigned short* __restrict__ Ko,
    unsigned short* __restrict__ Vo, const int* __restrict__ lens) {
  const int z = blockIdx.z;
  const int m0 = blockIdx.y * 128, n0 = blockIdx.x * 128;
  const int b = m0 >> 11;
  const int len = (z == 0) ? lens[2 + b] : lens[b];
  if ((m0 & (SEQ - 1)) >= len) return;  // rows never read downstream (poison benign)

  const unsigned short* x = (z == 0) ? xq : (z == 1) ? xk : xv;
  const unsigned short* W = (z == 0) ? Wq : (z == 1) ? Wk : Wv;
  const float* bias = (z == 0) ? bq : (z == 1) ? bk : bv;
  unsigned short* dst = (z == 0) ? Qo : (z == 1) ? Ko : Vo;
  const float osc = (z == 0) ? 0.18033688011112042f : 1.0f;

  __shared__ unsigned short As[128 * 64];  // row=64 shorts, 8x16B groups, swizzle row&7
  __shared__ unsigned short Bs[128 * 64];

  const int t = threadIdx.x;
  const int wave = t >> 6, lane = t & 63, quad = lane >> 4, l16 = lane & 15;
  const int wm = wave >> 1, wn = wave & 1;

  const f32x4 fz = {0.f, 0.f, 0.f, 0.f};
  f32x4 acc[4][4];
#pragma unroll
  for (int i = 0; i < 4; i++)
#pragma unroll
    for (int j = 0; j < 4; j++) acc[i][j] = fz;

  for (int k0 = 0; k0 < DMODEL; k0 += 64) {
    __syncthreads();
#pragma unroll
    for (int c = 0; c < 4; c++) {
      const int slot = c * 256 + t;
      const int row = slot >> 3, pg = slot & 7;
      const int lg = (pg ^ (row & 7)) * 8;
      async_copy16(x + (size_t)(m0 + row) * DMODEL + k0 + lg,
                   (char*)As + (c * 256 + (t & 192)) * 16);
      async_copy16(W + (size_t)(n0 + row) * DMODEL + k0 + lg,
                   (char*)Bs + (c * 256 + (t & 192)) * 16);
    }
    __syncthreads();
#pragma unroll
    for (int kk = 0; kk < 2; kk++) {
      bf16x8 af[4], bfr[4];
#pragma unroll
      for (int i = 0; i < 4; i++) {
        const int ra = wm * 64 + i * 16 + l16;
        const int rb = wn * 64 + i * 16 + l16;
        af[i] = *(const bf16x8*)(As + ra * 64 + ((kk * 4 + quad) ^ (ra & 7)) * 8);
        bfr[i] = *(const bf16x8*)(Bs + rb * 64 + ((kk * 4 + quad) ^ (rb & 7)) * 8);
      }
      if (z == 2) {
#pragma unroll
        for (int i = 0; i < 4; i++)
#pragma unroll
          for (int j = 0; j < 4; j++)
            acc[i][j] = __builtin_amdgcn_mfma_f32_16x16x32_bf16(af[i], bfr[j], acc[i][j], 0, 0, 0);
      } else {
#pragma unroll
        for (int i = 0; i < 4; i++)
#pragma unroll
          for (int j = 0; j < 4; j++)
            acc[i][j] = __builtin_amdgcn_mfma_f32_16x16x32_bf16(bfr[j], af[i], acc[i][j], 0, 0, 0);
      }
    }
  }

  if (z == 2) {
    // acc rows (quad*4+r) = s, cols (l16) = n -> V^T[b,h,hd,s]: 4 consecutive s
#pragma unroll
    for (int j = 0; j < 4; j++) {
      const int n = n0 + wn * 64 + j * 16 + l16;
      const float bb_ = bias[n];
      const int h = n >> 6, hd = n & 63;
#pragma unroll
      for (int i = 0; i < 4; i++) {
        const int s0 = (m0 & (SEQ - 1)) + wm * 64 + i * 16 + quad * 4;
        uint2 w;
        w.x = pk2bf(acc[i][j][0] + bb_, acc[i][j][1] + bb_);
        w.y = pk2bf(acc[i][j][2] + bb_, acc[i][j][3] + bb_);
        *(uint2*)(dst + (((size_t)(b * NHEAD + h) * HDIM + hd) << 11) + s0) = w;
      }
    }
  } else {
    // acc rows (quad*4+r) = n, cols (l16) = s -> [b,h,s,hd]: 4 consecutive hd
#pragma unroll
    for (int j = 0; j < 4; j++) {
      const int nb = n0 + wn * 64 + j * 16 + quad * 4;
      const float4 b4 = *(const float4*)(bias + nb);
      const int h = nb >> 6, hd0 = nb & 63;
#pragma unroll
      for (int i = 0; i < 4; i++) {
        const int s = (m0 & (SEQ - 1)) + wm * 64 + i * 16 + l16;
        uint2 w;
        w.x = pk2bf((acc[i][j][0] + b4.x) * osc, (acc[i][j][1] + b4.y) * osc);
        w.y = pk2bf((acc[i][j][2] + b4.z) * osc, (acc[i][j][3] + b4.w) * osc);
        *(uint2*)(dst + (((size_t)(b * NHEAD + h) * SEQ + s) << 6) + hd0) = w;
      }
    }
  }
}

// ===== attention v11 (R5, best measured 50.2us): ADJACENT tile pairs ========
// pair (2p, 2p+1) on wave groups 0-3/4-7: ktots differ by <=1, every staged
// tile serves both groups; Sigma iters/bh = 272. Cost balance p = b ? x : 15-x.
// KVB=64 dbuf single-barrier pipeline + defer-max + setprio. 48KB -> 2 blk/CU.

#define KVB 64

template <bool MASKED>
__device__ __forceinline__ void softmax_update(
    const f32x4 s[4], int key0, int qrow, int klen, int quad, int l16,
    float& mst, float& lsum, f32x4 o[4], unsigned short* Pdst) {
  float pm[4][4];
  float rm = -__builtin_inff();
  if (MASKED) {
    const int kmax = ((qrow < klen - 1) ? qrow : klen - 1) - key0 - quad * 4;
#pragma unroll
    for (int nf = 0; nf < 4; nf++)
#pragma unroll
      for (int r = 0; r < 4; r++) {
        pm[nf][r] = (nf * 16 + r <= kmax) ? s[nf][r] : -__builtin_inff();
        rm = fmaxf(rm, pm[nf][r]);
      }
  } else {
#pragma unroll
    for (int nf = 0; nf < 4; nf++)
#pragma unroll
      for (int r = 0; r < 4; r++) {
        pm[nf][r] = s[nf][r];
        rm = fmaxf(rm, pm[nf][r]);
      }
  }
  // combine the 4 quads of each q-row (row = l16): lanes l16, +16, +32, +48
  rm = fmaxf(rm, __shfl_xor(rm, 16, 64));
  rm = fmaxf(rm, __shfl_xor(rm, 32, 64));
  // defer-max (T13): rescale only when any row grows by >8 in exp2-domain;
  // otherwise P <= 2^8 = 256, safe for f32 lsum/o accumulation.
  if (__ballot(rm > mst + 8.0f) != 0ull) {
    const float mnew = fmaxf(mst, rm);
    const float alpha = exp2f(fmaxf(mst, -1e30f) - fmaxf(mnew, -1e30f));
    mst = mnew;
    lsum *= alpha;
    float ab[4];
#pragma unroll
    for (int r = 0; r < 4; r++) ab[r] = __shfl(alpha, quad * 4 + r, 64);
#pragma unroll
    for (int db = 0; db < 4; db++)
#pragma unroll
      for (int r = 0; r < 4; r++) o[db][r] *= ab[r];
  }
  const float mref = fmaxf(mst, -1e30f);
  float rs = 0.f;
#pragma unroll
  for (int nf = 0; nf < 4; nf++)
#pragma unroll
    for (int r = 0; r < 4; r++) {
      const float p = exp2f(pm[nf][r] - mref);
      pm[nf][r] = p;
      rs += p;
    }
  rs += __shfl_xor(rs, 16, 64);
  rs += __shfl_xor(rs, 32, 64);
  lsum += rs;
  // P[q=l16][key=16nf+4quad+r] -> 16B group g=2nf+(quad>>1), half (quad&1)
#pragma unroll
  for (int nf = 0; nf < 4; nf++) {
    uint2 w;
    w.x = pk2bf(pm[nf][0], pm[nf][1]);
    w.y = pk2bf(pm[nf][2], pm[nf][3]);
    const int g = (nf * 2 + (quad >> 1)) ^ (l16 & 7);
    *(uint2*)(Pdst + l16 * KVB + g * 8 + (quad & 1) * 4) = w;
  }
}

template <bool MASKED>
__device__ __forceinline__ void tile_pass(
    const unsigned short* __restrict__ ks, const unsigned short* __restrict__ vt,
    unsigned short* __restrict__ Pw, bf16x8 qf0, bf16x8 qf1,
    int key0, int qrow, int klen, int quad, int l16,
    float& mst, float& lsum, f32x4 o[4]) {
  const f32x4 fz = {0.f, 0.f, 0.f, 0.f};
  f32x4 s[4];
  __builtin_amdgcn_s_setprio(1);
#pragma unroll
  for (int nf = 0; nf < 4; nf++) {
    const int row = nf * 16 + l16;
    const int sw = row & 7;
    const bf16x8 kf0 = *(const bf16x8*)(ks + row * 64 + (quad ^ sw) * 8);
    const bf16x8 kf1 = *(const bf16x8*)(ks + row * 64 + ((quad + 4) ^ sw) * 8);
    f32x4 a = fz;
    a = __builtin_amdgcn_mfma_f32_16x16x32_bf16(kf0, qf0, a, 0, 0, 0);
    a = __builtin_amdgcn_mfma_f32_16x16x32_bf16(kf1, qf1, a, 0, 0, 0);
    s[nf] = a;
  }
  __builtin_amdgcn_s_setprio(0);
  softmax_update<MASKED>(s, key0, qrow, klen, quad, l16, mst, lsum, o, Pw);
  bf16x8 pf[2];
#pragma unroll
  for (int ksn = 0; ksn < 2; ksn++)
    pf[ksn] = *(const bf16x8*)(Pw + l16 * KVB + ((ksn * 4 + quad) ^ (l16 & 7)) * 8);
  __builtin_amdgcn_s_setprio(1);
#pragma unroll
  for (int db = 0; db < 4; db++) {
    const int d = db * 16 + l16;
    const int sw = d & 7;
#pragma unroll
    for (int ksn = 0; ksn < 2; ksn++) {
      const bf16x8 v = *(const bf16x8*)(vt + d * KVB + ((ksn * 4 + quad) ^ sw) * 8);
      o[db] = __builtin_amdgcn_mfma_f32_16x16x32_bf16(pf[ksn], v, o[db], 0, 0, 0);
    }
  }
  __builtin_amdgcn_s_setprio(0);
}

__global__ __launch_bounds__(512, 2) void attn_kernel(
    const unsigned short* __restrict__ Qb, const unsigned short* __restrict__ Kb,
    const unsigned short* __restrict__ VTb, const float* __restrict__ qin,
    const int* __restrict__ lens, float* __restrict__ out) {
  const int pi = blockIdx.x, h = blockIdx.y, b = blockIdx.z;
  const int bh = b * NHEAD + h;
  const int t = threadIdx.x, wave = t >> 6, lane = t & 63, quad = lane >> 4, l16 = lane & 15;
  const int grp = wave >> 2, w4 = wave & 3;  // grp 0: tile 2p, grp 1: tile 2p+1
  const int x = (pi + h) & 15;
  const int p = b ? x : 15 - x;  // b=0 half dispatches first: big blocks first
  const int myTile = 2 * p + grp;
  const int klen = lens[b], qlen = lens[2 + b];

  __shared__ unsigned short Ks[2][KVB * 64];  // [key][d], swizzle row&7, 8KB each
  __shared__ unsigned short VT[2][KVB * 64];  // [d][key], swizzle d&7, 8KB each
  __shared__ unsigned short Ps[8][16 * KVB];  // per-wave P, 2KB each
  // total 48KB

  const unsigned short* Qp = Qb + (size_t)bh * SEQ * HDIM;
  const unsigned short* Kp = Kb + (size_t)bh * SEQ * HDIM;
  const unsigned short* Vt = VTb + (size_t)bh * HDIM * SEQ;

  const int qrow = myTile * 64 + w4 * 16 + l16;
  const bf16x8 qf0 = *(const bf16x8*)(Qp + (size_t)qrow * HDIM + quad * 8);
  const bf16x8 qf1 = *(const bf16x8*)(Qp + (size_t)qrow * HDIM + 32 + quad * 8);

  const f32x4 fz = {0.f, 0.f, 0.f, 0.f};
  f32x4 o[4];
#pragma unroll
  for (int i = 0; i < 4; i++) o[i] = fz;
  float mst = -__builtin_inff(), lsum = 0.f;

  // per-group iteration counts in 64-key units (adjacent tiles: differ by <=1)
  const int tA = 2 * p, tB = 2 * p + 1;
  const int kendA = ((tA * 64 + 64) < klen) ? (tA * 64 + 64) : klen;
  const int kendB = ((tB * 64 + 64) < klen) ? (tB * 64 + 64) : klen;
  const int ktA = (tA * 64 < qlen) ? ((kendA + 63) >> 6) : 0;
  const int ktB = (tB * 64 < qlen) ? ((kendB + 63) >> 6) : 0;
  const int ktot = (ktA > ktB) ? ktA : ktB;
  const int myt = grp ? ktB : ktA;

  // stage K/V 64-key tile kt into buffer buf: 512 threads x (1 K + 1 V)
  auto STAGE = [&](int buf, int kt) {
    const int key0 = kt << 6;
    const int row = t >> 3;
    const int sg = ((t & 7) ^ (row & 7)) * 8;  // pre-swizzled source (rule 21)
    async_copy16(Kp + (size_t)(key0 + row) * HDIM + sg,
                 (char*)Ks[buf] + (t & 448) * 16);
    async_copy16(Vt + (size_t)row * SEQ + key0 + sg,
                 (char*)VT[buf] + (t & 448) * 16);
  };

  STAGE(0, 0);
  __syncthreads();  // drains vmcnt(0): buf0 ready
  int cur = 0;
  for (int kt = 0; kt < ktot; kt++) {
    if (kt + 1 < ktot) STAGE(cur ^ 1, kt + 1);  // overlaps with compute below
    if (kt < myt) {
      const int key0 = kt << 6;
      if ((key0 + 63 <= myTile * 64 + w4 * 16) && (key0 + 63 < klen))
        tile_pass<false>(Ks[cur], VT[cur], Ps[wave], qf0, qf1, key0, qrow,
                         klen, quad, l16, mst, lsum, o);
      else
        tile_pass<true>(Ks[cur], VT[cur], Ps[wave], qf0, qf1, key0, qrow,
                        klen, quad, l16, mst, lsum, o);
    }
    __syncthreads();  // drains next-tile staging + all LDS reads of cur
    cur ^= 1;
  }

  const float inv = (lsum > 0.f) ? 1.f / lsum : 0.f;
  float ib[4];
#pragma unroll
  for (int r = 0; r < 4; r++) ib[r] = __shfl(inv, quad * 4 + r, 64);
#pragma unroll
  for (int db = 0; db < 4; db++) {
    const int col = h * HDIM + db * 16 + l16;
#pragma unroll
    for (int r = 0; r < 4; r++) {
      const int i = myTile * 64 + w4 * 16 + quad * 4 + r;
      const size_t oo = (size_t)(b * SEQ + i) * DMODEL + col;
      out[oo] = ((i < qlen) ? o[db][r] * ib[r] : 0.f) + qin[oo];
    }
  }
}

extern "C" void kernel_launch(void* const* d_in, const int* in_sizes, int n_in,
                              void* d_out, int out_size, void* d_ws, size_t ws_size,
                              hipStream_t stream) {
  (void)in_sizes; (void)n_in; (void)out_size; (void)ws_size;
  const float* q = (const float*)d_in[0];
  const float* k = (const float*)d_in[1];
  const float* v = (const float*)d_in[2];
  const float* Wq = (const float*)d_in[3];
  const float* bq = (const float*)d_in[4];
  const float* Wk = (const float*)d_in[5];
  const float* bk = (const float*)d_in[6];
  const float* Wv = (const float*)d_in[7];
  const float* bv = (const float*)d_in[8];
  const unsigned char* kpm = (const unsigned char*)d_in[9];
  const unsigned char* qpm = (const unsigned char*)d_in[10];
  float* out = (float*)d_out;

  const size_t tsz = (size_t)BATCH * SEQ * DMODEL;  // 4 Mi
  const size_t wsz = (size_t)DMODEL * DMODEL;       // 1 Mi

  char* ws = (char*)d_ws;
  int* lens = (int*)ws;
  unsigned short* cvt_base = (unsigned short*)(ws + 256);
  unsigned short* qb16 = cvt_base;
  unsigned short* kb16 = qb16 + tsz;
  unsigned short* vb16 = kb16 + tsz;
  unsigned short* Wqb = vb16 + tsz;
  unsigned short* Wkb = Wqb + wsz;
  unsigned short* Wvb = Wkb + wsz;
  unsigned short* Qw = Wvb + wsz;
  unsigned short* Kw = Qw + tsz;
  unsigned short* Vtw = Kw + tsz;  // V^T [b,h,d,s]

  cvt_all<<<dim3(CVT_BLOCKS + 1), dim3(256), 0, stream>>>(q, k, v, Wq, Wk, Wv,
                                                          cvt_base, kpm, qpm, lens);
  qkv_proj<<<dim3(8, 32, 3), dim3(256), 0, stream>>>(qb16, kb16, vb16, Wqb, bq, Wkb, bk, Wvb, bv, Qw, Kw, Vtw, lens);
  attn_kernel<<<dim3(16, NHEAD, BATCH), dim3(512), 0, stream>>>(Qw, Kw, Vtw, q, lens, out);
}

// Round 13
// 201.157 us; speedup vs baseline: 1.1176x; 1.0064x over previous
//
#include <hip/hip_runtime.h>
#include <stdint.h>

#define BATCH 2
#define SEQ 2048
#define DMODEL 1024
#define NHEAD 16
#define HDIM 64
#define CVT_BLOCKS 7680

typedef __attribute__((ext_vector_type(8))) short bf16x8;
typedef __attribute__((ext_vector_type(8))) short short8;
typedef __attribute__((ext_vector_type(4))) float f32x4;

__device__ __forceinline__ unsigned short f2bf(float f) {
  unsigned int u = __float_as_uint(f);
  u += 0x7fffu + ((u >> 16) & 1u);
  return (unsigned short)(u >> 16);
}
// pack 2 f32 -> 2 bf16 (round-to-nearest-ties-away): 2 adds + 1 v_perm
__device__ __forceinline__ unsigned int pk2bf(float a, float b) {
  return __builtin_amdgcn_perm(__float_as_uint(b) + 0x8000u,
                               __float_as_uint(a) + 0x8000u, 0x07060302u);
}
__device__ __forceinline__ void async_copy16(const void* g, void* l) {
  __builtin_amdgcn_global_load_lds(
      (const __attribute__((address_space(1))) void*)g,
      (__attribute__((address_space(3))) void*)l, 16, 0, 0);
}

// ---- fp32 -> bf16 for q,k,v,Wq,Wk,Wv (32B/lane); block CVT_BLOCKS: lens ----
__global__ __launch_bounds__(256) void cvt_all(
    const float* __restrict__ q, const float* __restrict__ k,
    const float* __restrict__ v, const float* __restrict__ Wq,
    const float* __restrict__ Wk, const float* __restrict__ Wv,
    unsigned short* __restrict__ dst,
    const unsigned char* __restrict__ kp, const unsigned char* __restrict__ qp,
    int* __restrict__ lens) {
  if (blockIdx.x == CVT_BLOCKS) {  // klen->lens[0..1], qlen->lens[2..3]
    const int t = threadIdx.x, wave = t >> 6, lane = t & 63;
    const unsigned char* base = (wave < 2) ? kp : qp;
    const int b = wave & 1;
    const bool bytefmt = (base[1] != 0);  // element 1 always valid (len>=S/2)
    int cnt = 0;
    if (bytefmt) {
      const uint4* p = (const uint4*)(base + (size_t)b * SEQ);
#pragma unroll
      for (int g = 0; g < 2; g++) {
        const uint4 x = p[g * 64 + lane];
        const unsigned int w[4] = {x.x, x.y, x.z, x.w};
#pragma unroll
        for (int i = 0; i < 4; i++) {
          const unsigned int ww = w[i];
          cnt += ((ww & 0xffu) != 0) + ((ww & 0xff00u) != 0) +
                 ((ww & 0xff0000u) != 0) + ((ww & 0xff000000u) != 0);
        }
      }
    } else {
      const uint4* p = (const uint4*)(base + (size_t)b * SEQ * 4);
#pragma unroll
      for (int g = 0; g < 8; g++) {
        const uint4 x = p[g * 64 + lane];
        cnt += (x.x != 0) + (x.y != 0) + (x.z != 0) + (x.w != 0);
      }
    }
#pragma unroll
    for (int off = 32; off >= 1; off >>= 1) cnt += __shfl_xor(cnt, off, 64);
    if (lane == 0) lens[wave] = cnt;
    return;
  }
  const int g = blockIdx.x * 256 + threadIdx.x;
  const float* src;
  size_t off, dbase;  // off in float4 units (2 consecutive per thread)
  if (g < 3 * (1 << 19)) {
    const int ti = g >> 19;
    src = (ti == 0) ? q : (ti == 1) ? k : v;
    off = (size_t)(g & ((1 << 19) - 1)) * 2;
    dbase = (size_t)ti << 22;
  } else {
    const int gw = g - 3 * (1 << 19);
    const int ti = gw >> 17;
    src = (ti == 0) ? Wq : (ti == 1) ? Wk : Wv;
    off = (size_t)(gw & ((1 << 17) - 1)) * 2;
    dbase = (3ull << 22) + ((size_t)ti << 20);
  }
  const float4 x0 = ((const float4*)src)[off];
  const float4 x1 = ((const float4*)src)[off + 1];
  short8 o;
  o[0] = (short)f2bf(x0.x); o[1] = (short)f2bf(x0.y);
  o[2] = (short)f2bf(x0.z); o[3] = (short)f2bf(x0.w);
  o[4] = (short)f2bf(x1.x); o[5] = (short)f2bf(x1.y);
  o[6] = (short)f2bf(x1.z); o[7] = (short)f2bf(x1.w);
  *(short8*)(dst + dbase + off * 4) = o;
}

// ---- fused QKV projection v2 (R5-proven) + T1 XCD swizzle.
// HW dispatches consecutive block ids round-robin over 8 XCDs; un-swizzled,
// the 8 n-blocks sharing one A-tile land on 8 different L2s. Remap
// swz = (bid&7)*32 + bid>>3 (bijective, 256=8*32 per z): each XCD owns a
// contiguous 4-m-tile A-panel (1MB, L2-resident) across all n-tiles.
// Q pre-scaled by (1/sqrt(64))*log2(e). Q/K: swapped mfma -> acc rows=out-dim.
// V: normal mfma -> acc rows = seq -> writes V^T[b,h,d,s].
__global__ __launch_bounds__(256) void qkv_proj(
    const unsigned short* __restrict__ xq, const unsigned short* __restrict__ xk,
    const unsigned short* __restrict__ xv,
    const unsigned short* __restrict__ Wq, const float* __restrict__ bq,
    const unsigned short* __restrict__ Wk, const float* __restrict__ bk,
    const unsigned short* __restrict__ Wv, const float* __restrict__ bv,
    unsigned short* __restrict__ Qo, unsigned short* __restrict__ Ko,
    unsigned short* __restrict__ Vo, const int* __restrict__ lens) {
  const int z = blockIdx.z;
  const int bid = blockIdx.x + (blockIdx.y << 3);  // 0..255 within z, x fastest
  const int swz = (bid & 7) * 32 + (bid >> 3);     // bijective XCD remap (T1)
  const int m0 = (swz >> 3) * 128, n0 = (swz & 7) * 128;
  const int b = m0 >> 11;
  const int len = (z == 0) ? lens[2 + b] : lens[b];
  if ((m0 & (SEQ - 1)) >= len) return;  // rows never read downstream (poison benign)

  const unsigned short* x = (z == 0) ? xq : (z == 1) ? xk : xv;
  const unsigned short* W = (z == 0) ? Wq : (z == 1) ? Wk : Wv;
  const float* bias = (z == 0) ? bq : (z == 1) ? bk : bv;
  unsigned short* dst = (z == 0) ? Qo : (z == 1) ? Ko : Vo;
  const float osc = (z == 0) ? 0.18033688011112042f : 1.0f;

  __shared__ unsigned short As[128 * 64];  // row=64 shorts, 8x16B groups, swizzle row&7
  __shared__ unsigned short Bs[128 * 64];

  const int t = threadIdx.x;
  const int wave = t >> 6, lane = t & 63, quad = lane >> 4, l16 = lane & 15;
  const int wm = wave >> 1, wn = wave & 1;

  const f32x4 fz = {0.f, 0.f, 0.f, 0.f};
  f32x4 acc[4][4];
#pragma unroll
  for (int i = 0; i < 4; i++)
#pragma unroll
    for (int j = 0; j < 4; j++) acc[i][j] = fz;

  for (int k0 = 0; k0 < DMODEL; k0 += 64) {
    __syncthreads();
#pragma unroll
    for (int c = 0; c < 4; c++) {
      const int slot = c * 256 + t;
      const int row = slot >> 3, pg = slot & 7;
      const int lg = (pg ^ (row & 7)) * 8;
      async_copy16(x + (size_t)(m0 + row) * DMODEL + k0 + lg,
                   (char*)As + (c * 256 + (t & 192)) * 16);
      async_copy16(W + (size_t)(n0 + row) * DMODEL + k0 + lg,
                   (char*)Bs + (c * 256 + (t & 192)) * 16);
    }
    __syncthreads();
#pragma unroll
    for (int kk = 0; kk < 2; kk++) {
      bf16x8 af[4], bfr[4];
#pragma unroll
      for (int i = 0; i < 4; i++) {
        const int ra = wm * 64 + i * 16 + l16;
        const int rb = wn * 64 + i * 16 + l16;
        af[i] = *(const bf16x8*)(As + ra * 64 + ((kk * 4 + quad) ^ (ra & 7)) * 8);
        bfr[i] = *(const bf16x8*)(Bs + rb * 64 + ((kk * 4 + quad) ^ (rb & 7)) * 8);
      }
      if (z == 2) {
#pragma unroll
        for (int i = 0; i < 4; i++)
#pragma unroll
          for (int j = 0; j < 4; j++)
            acc[i][j] = __builtin_amdgcn_mfma_f32_16x16x32_bf16(af[i], bfr[j], acc[i][j], 0, 0, 0);
      } else {
#pragma unroll
        for (int i = 0; i < 4; i++)
#pragma unroll
          for (int j = 0; j < 4; j++)
            acc[i][j] = __builtin_amdgcn_mfma_f32_16x16x32_bf16(bfr[j], af[i], acc[i][j], 0, 0, 0);
      }
    }
  }

  if (z == 2) {
    // acc rows (quad*4+r) = s, cols (l16) = n -> V^T[b,h,hd,s]: 4 consecutive s
#pragma unroll
    for (int j = 0; j < 4; j++) {
      const int n = n0 + wn * 64 + j * 16 + l16;
      const float bb_ = bias[n];
      const int h = n >> 6, hd = n & 63;
#pragma unroll
      for (int i = 0; i < 4; i++) {
        const int s0 = (m0 & (SEQ - 1)) + wm * 64 + i * 16 + quad * 4;
        uint2 w;
        w.x = pk2bf(acc[i][j][0] + bb_, acc[i][j][1] + bb_);
        w.y = pk2bf(acc[i][j][2] + bb_, acc[i][j][3] + bb_);
        *(uint2*)(dst + (((size_t)(b * NHEAD + h) * HDIM + hd) << 11) + s0) = w;
      }
    }
  } else {
    // acc rows (quad*4+r) = n, cols (l16) = s -> [b,h,s,hd]: 4 consecutive hd
#pragma unroll
    for (int j = 0; j < 4; j++) {
      const int nb = n0 + wn * 64 + j * 16 + quad * 4;
      const float4 b4 = *(const float4*)(bias + nb);
      const int h = nb >> 6, hd0 = nb & 63;
#pragma unroll
      for (int i = 0; i < 4; i++) {
        const int s = (m0 & (SEQ - 1)) + wm * 64 + i * 16 + l16;
        uint2 w;
        w.x = pk2bf((acc[i][j][0] + b4.x) * osc, (acc[i][j][1] + b4.y) * osc);
        w.y = pk2bf((acc[i][j][2] + b4.z) * osc, (acc[i][j][3] + b4.w) * osc);
        *(uint2*)(dst + (((size_t)(b * NHEAD + h) * SEQ + s) << 6) + hd0) = w;
      }
    }
  }
}

// ===== attention v11 (R5/R12, best measured): ADJACENT tile pairs ===========
// pair (2p, 2p+1) on wave groups 0-3/4-7: ktots differ by <=1, every staged
// tile serves both groups; Sigma iters/bh = 272. Cost balance p = b ? x : 15-x.
// KVB=64 dbuf single-barrier pipeline + defer-max + setprio. 48KB -> 2 blk/CU.

#define KVB 64

template <bool MASKED>
__device__ __forceinline__ void softmax_update(
    const f32x4 s[4], int key0, int qrow, int klen, int quad, int l16,
    float& mst, float& lsum, f32x4 o[4], unsigned short* Pdst) {
  float pm[4][4];
  float rm = -__builtin_inff();
  if (MASKED) {
    const int kmax = ((qrow < klen - 1) ? qrow : klen - 1) - key0 - quad * 4;
#pragma unroll
    for (int nf = 0; nf < 4; nf++)
#pragma unroll
      for (int r = 0; r < 4; r++) {
        pm[nf][r] = (nf * 16 + r <= kmax) ? s[nf][r] : -__builtin_inff();
        rm = fmaxf(rm, pm[nf][r]);
      }
  } else {
#pragma unroll
    for (int nf = 0; nf < 4; nf++)
#pragma unroll
      for (int r = 0; r < 4; r++) {
        pm[nf][r] = s[nf][r];
        rm = fmaxf(rm, pm[nf][r]);
      }
  }
  // combine the 4 quads of each q-row (row = l16): lanes l16, +16, +32, +48
  rm = fmaxf(rm, __shfl_xor(rm, 16, 64));
  rm = fmaxf(rm, __shfl_xor(rm, 32, 64));
  // defer-max (T13): rescale only when any row grows by >8 in exp2-domain;
  // otherwise P <= 2^8 = 256, safe for f32 lsum/o accumulation.
  if (__ballot(rm > mst + 8.0f) != 0ull) {
    const float mnew = fmaxf(mst, rm);
    const float alpha = exp2f(fmaxf(mst, -1e30f) - fmaxf(mnew, -1e30f));
    mst = mnew;
    lsum *= alpha;
    float ab[4];
#pragma unroll
    for (int r = 0; r < 4; r++) ab[r] = __shfl(alpha, quad * 4 + r, 64);
#pragma unroll
    for (int db = 0; db < 4; db++)
#pragma unroll
      for (int r = 0; r < 4; r++) o[db][r] *= ab[r];
  }
  const float mref = fmaxf(mst, -1e30f);
  float rs = 0.f;
#pragma unroll
  for (int nf = 0; nf < 4; nf++)
#pragma unroll
    for (int r = 0; r < 4; r++) {
      const float p = exp2f(pm[nf][r] - mref);
      pm[nf][r] = p;
      rs += p;
    }
  rs += __shfl_xor(rs, 16, 64);
  rs += __shfl_xor(rs, 32, 64);
  lsum += rs;
  // P[q=l16][key=16nf+4quad+r] -> 16B group g=2nf+(quad>>1), half (quad&1)
#pragma unroll
  for (int nf = 0; nf < 4; nf++) {
    uint2 w;
    w.x = pk2bf(pm[nf][0], pm[nf][1]);
    w.y = pk2bf(pm[nf][2], pm[nf][3]);
    const int g = (nf * 2 + (quad >> 1)) ^ (l16 & 7);
    *(uint2*)(Pdst + l16 * KVB + g * 8 + (quad & 1) * 4) = w;
  }
}

template <bool MASKED>
__device__ __forceinline__ void tile_pass(
    const unsigned short* __restrict__ ks, const unsigned short* __restrict__ vt,
    unsigned short* __restrict__ Pw, bf16x8 qf0, bf16x8 qf1,
    int key0, int qrow, int klen, int quad, int l16,
    float& mst, float& lsum, f32x4 o[4]) {
  const f32x4 fz = {0.f, 0.f, 0.f, 0.f};
  f32x4 s[4];
  __builtin_amdgcn_s_setprio(1);
#pragma unroll
  for (int nf = 0; nf < 4; nf++) {
    const int row = nf * 16 + l16;
    const int sw = row & 7;
    const bf16x8 kf0 = *(const bf16x8*)(ks + row * 64 + (quad ^ sw) * 8);
    const bf16x8 kf1 = *(const bf16x8*)(ks + row * 64 + ((quad + 4) ^ sw) * 8);
    f32x4 a = fz;
    a = __builtin_amdgcn_mfma_f32_16x16x32_bf16(kf0, qf0, a, 0, 0, 0);
    a = __builtin_amdgcn_mfma_f32_16x16x32_bf16(kf1, qf1, a, 0, 0, 0);
    s[nf] = a;
  }
  __builtin_amdgcn_s_setprio(0);
  softmax_update<MASKED>(s, key0, qrow, klen, quad, l16, mst, lsum, o, Pw);
  bf16x8 pf[2];
#pragma unroll
  for (int ksn = 0; ksn < 2; ksn++)
    pf[ksn] = *(const bf16x8*)(Pw + l16 * KVB + ((ksn * 4 + quad) ^ (l16 & 7)) * 8);
  __builtin_amdgcn_s_setprio(1);
#pragma unroll
  for (int db = 0; db < 4; db++) {
    const int d = db * 16 + l16;
    const int sw = d & 7;
#pragma unroll
    for (int ksn = 0; ksn < 2; ksn++) {
      const bf16x8 v = *(const bf16x8*)(vt + d * KVB + ((ksn * 4 + quad) ^ sw) * 8);
      o[db] = __builtin_amdgcn_mfma_f32_16x16x32_bf16(pf[ksn], v, o[db], 0, 0, 0);
    }
  }
  __builtin_amdgcn_s_setprio(0);
}

__global__ __launch_bounds__(512, 2) void attn_kernel(
    const unsigned short* __restrict__ Qb, const unsigned short* __restrict__ Kb,
    const unsigned short* __restrict__ VTb, const float* __restrict__ qin,
    const int* __restrict__ lens, float* __restrict__ out) {
  const int pi = blockIdx.x, h = blockIdx.y, b = blockIdx.z;
  const int bh = b * NHEAD + h;
  const int t = threadIdx.x, wave = t >> 6, lane = t & 63, quad = lane >> 4, l16 = lane & 15;
  const int grp = wave >> 2, w4 = wave & 3;  // grp 0: tile 2p, grp 1: tile 2p+1
  const int x = (pi + h) & 15;
  const int p = b ? x : 15 - x;  // b=0 half dispatches first: big blocks first
  const int myTile = 2 * p + grp;
  const int klen = lens[b], qlen = lens[2 + b];

  __shared__ unsigned short Ks[2][KVB * 64];  // [key][d], swizzle row&7, 8KB each
  __shared__ unsigned short VT[2][KVB * 64];  // [d][key], swizzle d&7, 8KB each
  __shared__ unsigned short Ps[8][16 * KVB];  // per-wave P, 2KB each
  // total 48KB

  const unsigned short* Qp = Qb + (size_t)bh * SEQ * HDIM;
  const unsigned short* Kp = Kb + (size_t)bh * SEQ * HDIM;
  const unsigned short* Vt = VTb + (size_t)bh * HDIM * SEQ;

  const int qrow = myTile * 64 + w4 * 16 + l16;
  const bf16x8 qf0 = *(const bf16x8*)(Qp + (size_t)qrow * HDIM + quad * 8);
  const bf16x8 qf1 = *(const bf16x8*)(Qp + (size_t)qrow * HDIM + 32 + quad * 8);

  const f32x4 fz = {0.f, 0.f, 0.f, 0.f};
  f32x4 o[4];
#pragma unroll
  for (int i = 0; i < 4; i++) o[i] = fz;
  float mst = -__builtin_inff(), lsum = 0.f;

  // per-group iteration counts in 64-key units (adjacent tiles: differ by <=1)
  const int tA = 2 * p, tB = 2 * p + 1;
  const int kendA = ((tA * 64 + 64) < klen) ? (tA * 64 + 64) : klen;
  const int kendB = ((tB * 64 + 64) < klen) ? (tB * 64 + 64) : klen;
  const int ktA = (tA * 64 < qlen) ? ((kendA + 63) >> 6) : 0;
  const int ktB = (tB * 64 < qlen) ? ((kendB + 63) >> 6) : 0;
  const int ktot = (ktA > ktB) ? ktA : ktB;
  const int myt = grp ? ktB : ktA;

  // stage K/V 64-key tile kt into buffer buf: 512 threads x (1 K + 1 V)
  auto STAGE = [&](int buf, int kt) {
    const int key0 = kt << 6;
    const int row = t >> 3;
    const int sg = ((t & 7) ^ (row & 7)) * 8;  // pre-swizzled source (rule 21)
    async_copy16(Kp + (size_t)(key0 + row) * HDIM + sg,
                 (char*)Ks[buf] + (t & 448) * 16);
    async_copy16(Vt + (size_t)row * SEQ + key0 + sg,
                 (char*)VT[buf] + (t & 448) * 16);
  };

  STAGE(0, 0);
  __syncthreads();  // drains vmcnt(0): buf0 ready
  int cur = 0;
  for (int kt = 0; kt < ktot; kt++) {
    if (kt + 1 < ktot) STAGE(cur ^ 1, kt + 1);  // overlaps with compute below
    if (kt < myt) {
      const int key0 = kt << 6;
      if ((key0 + 63 <= myTile * 64 + w4 * 16) && (key0 + 63 < klen))
        tile_pass<false>(Ks[cur], VT[cur], Ps[wave], qf0, qf1, key0, qrow,
                         klen, quad, l16, mst, lsum, o);
      else
        tile_pass<true>(Ks[cur], VT[cur], Ps[wave], qf0, qf1, key0, qrow,
                        klen, quad, l16, mst, lsum, o);
    }
    __syncthreads();  // drains next-tile staging + all LDS reads of cur
    cur ^= 1;
  }

  const float inv = (lsum > 0.f) ? 1.f / lsum : 0.f;
  float ib[4];
#pragma unroll
  for (int r = 0; r < 4; r++) ib[r] = __shfl(inv, quad * 4 + r, 64);
#pragma unroll
  for (int db = 0; db < 4; db++) {
    const int col = h * HDIM + db * 16 + l16;
#pragma unroll
    for (int r = 0; r < 4; r++) {
      const int i = myTile * 64 + w4 * 16 + quad * 4 + r;
      const size_t oo = (size_t)(b * SEQ + i) * DMODEL + col;
      out[oo] = ((i < qlen) ? o[db][r] * ib[r] : 0.f) + qin[oo];
    }
  }
}

extern "C" void kernel_launch(void* const* d_in, const int* in_sizes, int n_in,
                              void* d_out, int out_size, void* d_ws, size_t ws_size,
                              hipStream_t stream) {
  (void)in_sizes; (void)n_in; (void)out_size; (void)ws_size;
  const float* q = (const float*)d_in[0];
  const float* k = (const float*)d_in[1];
  const float* v = (const float*)d_in[2];
  const float* Wq = (const float*)d_in[3];
  const float* bq = (const float*)d_in[4];
  const float* Wk = (const float*)d_in[5];
  const float* bk = (const float*)d_in[6];
  const float* Wv = (const float*)d_in[7];
  const float* bv = (const float*)d_in[8];
  const unsigned char* kpm = (const unsigned char*)d_in[9];
  const unsigned char* qpm = (const unsigned char*)d_in[10];
  float* out = (float*)d_out;

  const size_t tsz = (size_t)BATCH * SEQ * DMODEL;  // 4 Mi
  const size_t wsz = (size_t)DMODEL * DMODEL;       // 1 Mi

  char* ws = (char*)d_ws;
  int* lens = (int*)ws;
  unsigned short* cvt_base = (unsigned short*)(ws + 256);
  unsigned short* qb16 = cvt_base;
  unsigned short* kb16 = qb16 + tsz;
  unsigned short* vb16 = kb16 + tsz;
  unsigned short* Wqb = vb16 + tsz;
  unsigned short* Wkb = Wqb + wsz;
  unsigned short* Wvb = Wkb + wsz;
  unsigned short* Qw = Wvb + wsz;
  unsigned short* Kw = Qw + tsz;
  unsigned short* Vtw = Kw + tsz;  // V^T [b,h,d,s]

  cvt_all<<<dim3(CVT_BLOCKS + 1), dim3(256), 0, stream>>>(q, k, v, Wq, Wk, Wv,
                                                          cvt_base, kpm, qpm, lens);
  qkv_proj<<<dim3(8, 32, 3), dim3(256), 0, stream>>>(qb16, kb16, vb16, Wqb, bq, Wkb, bk, Wvb, bv, Qw, Kw, Vtw, lens);
  attn_kernel<<<dim3(16, NHEAD, BATCH), dim3(512), 0, stream>>>(Qw, Kw, Vtw, q, lens, out);
}